// Round 17
// baseline (317.658 us; speedup 1.0000x reference)
//
#include <hip/hip_runtime.h>
#include <math.h>

#define EPSBN 1e-5f
#define STAT_NCH 128

typedef _Float16 half8 __attribute__((ext_vector_type(8)));
typedef _Float16 half4v __attribute__((ext_vector_type(4)));
typedef float floatx4 __attribute__((ext_vector_type(4)));
typedef unsigned int uint32;

// --------------------------- KNN (top-16), 512 blocks x 512 thr, 16-way chunked
// 32 queries/block, 16 chunks of 128 candidates. LDS 76 KB -> with 512 blocks
// on 256 CUs, 2 blocks/CU co-resident (R16 showed 256 blocks = 1/CU was the
// occupancy blocker, not LDS capacity). VGPR ~52 (measured R16, no cap).
__global__ __launch_bounds__(512) void knn_kernel(const float* __restrict__ x,
                                                  int* __restrict__ idx)
{
    __shared__ float  xs[2048], ys[2048], sq[2048];   // 24 KB
    __shared__ float  md[16][32][17];                 // 34.8 KB
    __shared__ ushort mi[16][32][18];                 // 18.4 KB -> 76 KB total
    int b  = blockIdx.x >> 6;              // 64 blocks per batch
    int q0 = (blockIdx.x & 63) << 5;       // 32 queries per block
    const float* xb = x + (size_t)b * 2048 * 10;
    for (int j = threadIdx.x; j < 2048; j += 512) {
        float xj = xb[j * 10 + 0], yj = xb[j * 10 + 1];
        xs[j] = xj; ys[j] = yj;
        sq[j] = __fadd_rn(__fmul_rn(xj, xj), __fmul_rn(yj, yj));
    }
    __syncthreads();
    int qq    = threadIdx.x & 31;          // query within block
    int chunk = threadIdx.x >> 5;          // 0..15
    int i = q0 + qq;                       // query index within batch
    float xi = xs[i], yi = ys[i], sqi = sq[i];
    float bd[16]; int bi[16];
#pragma unroll
    for (int s = 0; s < 16; ++s) { bd[s] = INFINITY; bi[s] = 0; }
    int j0 = chunk << 7;                   // 128 candidates per chunk
    for (int jj = 0; jj < 128; ++jj) {
        int j = j0 + jj;
        float dot = __fadd_rn(__fmul_rn(xi, xs[j]), __fmul_rn(yi, ys[j]));
        float d   = __fsub_rn(__fadd_rn(sqi, sq[j]), __fmul_rn(2.0f, dot));
        if (j == i) d = INFINITY;
        if (d < bd[15]) {                  // strict < : ties keep lower index
            bd[15] = d; bi[15] = j;
#pragma unroll
            for (int s = 15; s > 0; --s) {
                if (bd[s] < bd[s - 1]) {
                    float td = bd[s]; bd[s] = bd[s - 1]; bd[s - 1] = td;
                    int   ti = bi[s]; bi[s] = bi[s - 1]; bi[s - 1] = ti;
                }
            }
        }
    }
#pragma unroll
    for (int s = 0; s < 16; ++s) { md[chunk][qq][s] = bd[s]; mi[chunk][qq][s] = (ushort)bi[s]; }
    __syncthreads();
    if (threadIdx.x < 32) {
        int q = threadIdx.x;
        float fd[16]; int fi[16];
#pragma unroll
        for (int s = 0; s < 16; ++s) { fd[s] = INFINITY; fi[s] = 0; }
        for (int c = 0; c < 16; ++c) {
            for (int s = 0; s < 16; ++s) {
                float d = md[c][q][s];
                if (!(d < fd[15])) break;  // sorted list: rest can't qualify
                int j = (int)mi[c][q][s];
                fd[15] = d; fi[15] = j;
#pragma unroll
                for (int t = 15; t > 0; --t) {
                    if (fd[t] < fd[t - 1]) {
                        float td = fd[t]; fd[t] = fd[t - 1]; fd[t - 1] = td;
                        int   ti = fi[t]; fi[t] = fi[t - 1]; fi[t - 1] = ti;
                    }
                }
            }
        }
        int* out = idx + (size_t)(b * 2048 + q0 + q) * 16;
#pragma unroll
        for (int s = 0; s < 16; ++s) out[s] = fi[s];
    }
}

// ---- fused covariance + 19-ch feature + 19->64 linear (4 threads/point)
__global__ __launch_bounds__(256) void cov_lin_kernel(const float* __restrict__ x,
                                                      const int* __restrict__ idx,
                                                      const float* __restrict__ w1a,
                                                      float* __restrict__ h0)
{
    __shared__ float ws_[19 * 64];
    for (int i = threadIdx.x; i < 19 * 64; i += 256) ws_[i] = w1a[i];
    __syncthreads();
    int gid = blockIdx.x * 256 + threadIdx.x;   // 0..65535
    int p   = gid >> 2;                          // point 0..16383
    int sub = gid & 3;
    int b   = p >> 11;
    const float* xb = x + ((size_t)(b << 11)) * 10;
    const int* ir = idx + (size_t)p * 16 + sub * 4;
    float sx = 0.f, sy = 0.f, se = 0.f;
    float sxx = 0.f, sxy = 0.f, sxe = 0.f;
    float syy = 0.f, sye = 0.f, see = 0.f;
#pragma unroll
    for (int k = 0; k < 4; ++k) {
        int nj = ir[k];
        const float* nr = xb + (size_t)nj * 10;
        float nx = nr[0], ny = nr[1];
        float ne = nr[2] + nr[3] + nr[4] + nr[5] + nr[6] + nr[7] + nr[8] + nr[9];
        sx += nx; sy += ny; se += ne;
        sxx += nx * nx; sxy += nx * ny; sxe += nx * ne;
        syy += ny * ny; sye += ny * ne; see += ne * ne;
    }
    const float* xr = x + (size_t)p * 10;
    float v0 = xr[0], v1 = xr[1], v2 = xr[2], v3 = xr[3], v4 = xr[4];
    float v5 = xr[5], v6 = xr[6], v7 = xr[7], v8 = xr[8], v9 = xr[9];
    float ec = v2 + v3 + v4 + v5 + v6 + v7 + v8 + v9;
    if (sub == 0) {
        sx += v0; sy += v1; se += ec;
        sxx += v0 * v0; sxy += v0 * v1; sxe += v0 * ec;
        syy += v1 * v1; sye += v1 * ec; see += ec * ec;
    }
    sx  += __shfl_xor(sx, 1);  sx  += __shfl_xor(sx, 2);
    sy  += __shfl_xor(sy, 1);  sy  += __shfl_xor(sy, 2);
    se  += __shfl_xor(se, 1);  se  += __shfl_xor(se, 2);
    sxx += __shfl_xor(sxx, 1); sxx += __shfl_xor(sxx, 2);
    sxy += __shfl_xor(sxy, 1); sxy += __shfl_xor(sxy, 2);
    sxe += __shfl_xor(sxe, 1); sxe += __shfl_xor(sxe, 2);
    syy += __shfl_xor(syy, 1); syy += __shfl_xor(syy, 2);
    sye += __shfl_xor(sye, 1); sye += __shfl_xor(sye, 2);
    see += __shfl_xor(see, 1); see += __shfl_xor(see, 2);
    const float inv = 1.0f / 17.0f;
    float mx = sx * inv, my = sy * inv, me = se * inv;
    float f[19];
    f[0] = v0; f[1] = v1; f[2] = v2; f[3] = v3; f[4] = v4;
    f[5] = v5; f[6] = v6; f[7] = v7; f[8] = v8; f[9] = v9;
    f[10] = sxx * inv - mx * mx; f[11] = sxy * inv - mx * my; f[12] = sxe * inv - mx * me;
    f[13] = f[11];               f[14] = syy * inv - my * my; f[15] = sye * inv - my * me;
    f[16] = f[12];               f[17] = f[15];               f[18] = see * inv - me * me;
    int c0 = sub << 4;
    float acc[16];
#pragma unroll
    for (int j = 0; j < 16; ++j) acc[j] = 0.f;
#pragma unroll
    for (int k = 0; k < 19; ++k) {
        float fv = f[k];
        const float* wr = &ws_[k * 64 + c0];
#pragma unroll
        for (int j = 0; j < 16; ++j) acc[j] = fmaf(fv, wr[j], acc[j]);
    }
    float* o = h0 + (size_t)p * 64 + c0;
#pragma unroll
    for (int j = 0; j < 16; j += 4) {
        float4 ov = {acc[j], acc[j + 1], acc[j + 2], acc[j + 3]};
        *(float4*)(o + j) = ov;
    }
}

// ---------------- fp32 tiled GEMM with fused input BN+ReLU on the A-load
__global__ __launch_bounds__(256) void gemm_bn_kernel(const float* __restrict__ A,
                                                      const float* __restrict__ B,
                                                      float* __restrict__ C,
                                                      const float* __restrict__ asc,
                                                      const float* __restrict__ ash,
                                                      int M, int N, int K)
{
    __shared__ float As[16][64];   // [k][row]
    __shared__ float Bs[16][64];   // [k][col]
    __shared__ float ssc[64], ssh[64];
    int t  = threadIdx.x;
    if (t < 64) { ssc[t] = asc[t]; ssh[t] = ash[t]; }
    int m0 = blockIdx.y << 6, n0 = blockIdx.x << 6;
    int arow = t >> 2, acol = (t & 3) << 2;
    int brow = t >> 4, bcol = (t & 15) << 2;
    int tr = (t >> 4) << 2, tc = (t & 15) << 2;
    float acc[4][4] = {};
    for (int k0 = 0; k0 < K; k0 += 16) {
        float4 av = *(const float4*)(A + (size_t)(m0 + arow) * K + k0 + acol);
        float4 bv = *(const float4*)(B + (size_t)(k0 + brow) * N + n0 + bcol);
        __syncthreads();
        int ka = k0 + acol;
        As[acol + 0][arow] = fmaxf(fmaf(av.x, ssc[ka + 0], ssh[ka + 0]), 0.f);
        As[acol + 1][arow] = fmaxf(fmaf(av.y, ssc[ka + 1], ssh[ka + 1]), 0.f);
        As[acol + 2][arow] = fmaxf(fmaf(av.z, ssc[ka + 2], ssh[ka + 2]), 0.f);
        As[acol + 3][arow] = fmaxf(fmaf(av.w, ssc[ka + 3], ssh[ka + 3]), 0.f);
        *(float4*)&Bs[brow][bcol] = bv;
        __syncthreads();
#pragma unroll
        for (int kk = 0; kk < 16; ++kk) {
            float4 a = *(const float4*)&As[kk][tr];
            float4 bb = *(const float4*)&Bs[kk][tc];
            float ar[4] = {a.x, a.y, a.z, a.w};
            float br[4] = {bb.x, bb.y, bb.z, bb.w};
#pragma unroll
            for (int i = 0; i < 4; ++i)
#pragma unroll
                for (int j = 0; j < 4; ++j)
                    acc[i][j] = fmaf(ar[i], br[j], acc[i][j]);
        }
    }
#pragma unroll
    for (int i = 0; i < 4; ++i) {
        float4 o;
        o.x = acc[i][0]; o.y = acc[i][1]; o.z = acc[i][2]; o.w = acc[i][3];
        *(float4*)(C + (size_t)(m0 + tr + i) * N + n0 + tc) = o;
    }
}

// ------------- fp16 MFMA GEMM, 128x128 tile, async global_load_lds staging
__global__ __launch_bounds__(256) void hgemm_kernel(const _Float16* __restrict__ A,
                                                    const _Float16* __restrict__ BT,
                                                    _Float16* __restrict__ C,
                                                    int M, int N, int K)
{
    __shared__ __align__(16) _Float16 As[2][4][128][8];
    __shared__ __align__(16) _Float16 Bs[2][4][128][8];
    int t = threadIdx.x;
    int m0 = blockIdx.y << 7, n0 = blockIdx.x << 7;
    int wv = t >> 6, lane = t & 63;
    int fr = lane & 15, fk = lane >> 4;
    int srow = t & 63, sk8 = t >> 6;
    const _Float16* Ab = A + (size_t)m0 * K + sk8 * 8;
    const _Float16* Bb = BT + (size_t)n0 * K + sk8 * 8;

    floatx4 zero = {0.f, 0.f, 0.f, 0.f};
    floatx4 acc[2][8];
#pragma unroll
    for (int i = 0; i < 2; ++i)
#pragma unroll
        for (int j = 0; j < 8; ++j) acc[i][j] = zero;

    int NC = K >> 5;

#define HG_STAGE(bf, kc)                                                                        \
    do {                                                                                        \
        int kb_ = (kc) << 5;                                                                    \
        __builtin_amdgcn_global_load_lds(                                                       \
            (const __attribute__((address_space(1))) uint32*)(Ab + (size_t)srow * K + kb_),     \
            (__attribute__((address_space(3))) uint32*)&As[bf][sk8][srow][0], 16, 0, 0);        \
        __builtin_amdgcn_global_load_lds(                                                       \
            (const __attribute__((address_space(1))) uint32*)(Ab + (size_t)(srow + 64) * K + kb_),\
            (__attribute__((address_space(3))) uint32*)&As[bf][sk8][srow + 64][0], 16, 0, 0);   \
        __builtin_amdgcn_global_load_lds(                                                       \
            (const __attribute__((address_space(1))) uint32*)(Bb + (size_t)srow * K + kb_),     \
            (__attribute__((address_space(3))) uint32*)&Bs[bf][sk8][srow][0], 16, 0, 0);        \
        __builtin_amdgcn_global_load_lds(                                                       \
            (const __attribute__((address_space(1))) uint32*)(Bb + (size_t)(srow + 64) * K + kb_),\
            (__attribute__((address_space(3))) uint32*)&Bs[bf][sk8][srow + 64][0], 16, 0, 0);   \
    } while (0)

    HG_STAGE(0, 0);
    __syncthreads();

    for (int kc = 0; kc < NC; ++kc) {
        int cur = kc & 1;
        if (kc + 1 < NC) HG_STAGE(cur ^ 1, kc + 1);
        half8 af[2];
#pragma unroll
        for (int mg = 0; mg < 2; ++mg)
            af[mg] = *(const half8*)&As[cur][fk][(wv << 5) + (mg << 4) + fr][0];
#pragma unroll
        for (int ng = 0; ng < 8; ++ng) {
            half8 bf = *(const half8*)&Bs[cur][fk][(ng << 4) + fr][0];
            acc[0][ng] = __builtin_amdgcn_mfma_f32_16x16x32_f16(af[0], bf, acc[0][ng], 0, 0, 0);
            acc[1][ng] = __builtin_amdgcn_mfma_f32_16x16x32_f16(af[1], bf, acc[1][ng], 0, 0, 0);
        }
        __syncthreads();
    }
#undef HG_STAGE
    int orow = m0 + (wv << 5) + (fk << 2);
#pragma unroll
    for (int mg = 0; mg < 2; ++mg)
#pragma unroll
        for (int ng = 0; ng < 8; ++ng)
#pragma unroll
            for (int i = 0; i < 4; ++i)
                C[(size_t)(orow + (mg << 4) + i) * N + n0 + (ng << 4) + fr] =
                    (_Float16)acc[mg][ng][i];
}

// ---------------- merged weight transpose+convert for both weights
__global__ __launch_bounds__(256) void wtrans2_kernel(const float* __restrict__ wa,
                                                      const float* __restrict__ wb,
                                                      _Float16* __restrict__ waT,
                                                      _Float16* __restrict__ wbT)
{
    int id = blockIdx.x * 256 + threadIdx.x;
    if (id < 64 * 512) {
        int k = id >> 9, n = id & 511;
        waT[(size_t)n * 64 + k] = (_Float16)wa[id];
    } else {
        int id2 = id - 64 * 512;
        int k = id2 >> 10, n = id2 & 1023;
        wbT[(size_t)n * 512 + k] = (_Float16)wb[id2];
    }
}

// --------------------------------------------------- BN stats (f32 input)
__global__ __launch_bounds__(256) void stats_part_kernel(const float* __restrict__ X,
                                                         int C,
                                                         float* __restrict__ ps,
                                                         float* __restrict__ pq)
{
    __shared__ float sl[256][4];
    __shared__ float ql[256][4];
    int t = threadIdx.x;
    int c = (blockIdx.x << 6) + ((t & 15) << 2);
    int rowsPer = 16384 / STAT_NCH;
    int r0 = blockIdx.y * rowsPer + (t >> 4);
    int rEnd = blockIdx.y * rowsPer + rowsPer;
    float4 s = {0.f, 0.f, 0.f, 0.f}, q = {0.f, 0.f, 0.f, 0.f};
    for (int r = r0; r < rEnd; r += 16) {
        float4 v = *(const float4*)(X + (size_t)r * C + c);
        s.x += v.x; s.y += v.y; s.z += v.z; s.w += v.w;
        q.x = fmaf(v.x, v.x, q.x); q.y = fmaf(v.y, v.y, q.y);
        q.z = fmaf(v.z, v.z, q.z); q.w = fmaf(v.w, v.w, q.w);
    }
    sl[t][0] = s.x; sl[t][1] = s.y; sl[t][2] = s.z; sl[t][3] = s.w;
    ql[t][0] = q.x; ql[t][1] = q.y; ql[t][2] = q.z; ql[t][3] = q.w;
    __syncthreads();
    if (t < 64) {
        int comp = t & 3, grp = t >> 2;
        float ss = 0.f, qq = 0.f;
#pragma unroll
        for (int g = 0; g < 16; ++g) {
            ss += sl[grp + (g << 4)][comp];
            qq += ql[grp + (g << 4)][comp];
        }
        ps[(size_t)blockIdx.y * C + (blockIdx.x << 6) + t] = ss;
        pq[(size_t)blockIdx.y * C + (blockIdx.x << 6) + t] = qq;
    }
}

// --------------------------------------------------- BN stats (f16 input)
__global__ __launch_bounds__(256) void stats_part_h_kernel(const _Float16* __restrict__ X,
                                                           int C,
                                                           float* __restrict__ ps,
                                                           float* __restrict__ pq)
{
    __shared__ float sl[256][4];
    __shared__ float ql[256][4];
    int t = threadIdx.x;
    int c = (blockIdx.x << 6) + ((t & 15) << 2);
    int rowsPer = 16384 / STAT_NCH;
    int r0 = blockIdx.y * rowsPer + (t >> 4);
    int rEnd = blockIdx.y * rowsPer + rowsPer;
    float4 s = {0.f, 0.f, 0.f, 0.f}, q = {0.f, 0.f, 0.f, 0.f};
    for (int r = r0; r < rEnd; r += 16) {
        half4v hv = *(const half4v*)(X + (size_t)r * C + c);
        float v0 = (float)hv[0], v1 = (float)hv[1], v2 = (float)hv[2], v3 = (float)hv[3];
        s.x += v0; s.y += v1; s.z += v2; s.w += v3;
        q.x = fmaf(v0, v0, q.x); q.y = fmaf(v1, v1, q.y);
        q.z = fmaf(v2, v2, q.z); q.w = fmaf(v3, v3, q.w);
    }
    sl[t][0] = s.x; sl[t][1] = s.y; sl[t][2] = s.z; sl[t][3] = s.w;
    ql[t][0] = q.x; ql[t][1] = q.y; ql[t][2] = q.z; ql[t][3] = q.w;
    __syncthreads();
    if (t < 64) {
        int comp = t & 3, grp = t >> 2;
        float ss = 0.f, qq = 0.f;
#pragma unroll
        for (int g = 0; g < 16; ++g) {
            ss += sl[grp + (g << 4)][comp];
            qq += ql[grp + (g << 4)][comp];
        }
        ps[(size_t)blockIdx.y * C + (blockIdx.x << 6) + t] = ss;
        pq[(size_t)blockIdx.y * C + (blockIdx.x << 6) + t] = qq;
    }
}

// ------------- BN stats + per-chunk raw max/min (f16 input, for f1024 path)
__global__ __launch_bounds__(256) void stats_minmax_part_h_kernel(const _Float16* __restrict__ X,
                                                                  int C,
                                                                  float* __restrict__ ps,
                                                                  float* __restrict__ pq,
                                                                  float* __restrict__ pmx,
                                                                  float* __restrict__ pmn)
{
    __shared__ float sl[256][4];
    __shared__ float ql[256][4];
    __shared__ float xl[256][4];
    __shared__ float nl[256][4];
    int t = threadIdx.x;
    int c = (blockIdx.x << 6) + ((t & 15) << 2);
    int rowsPer = 16384 / STAT_NCH;
    int r0 = blockIdx.y * rowsPer + (t >> 4);
    int rEnd = blockIdx.y * rowsPer + rowsPer;
    float4 s = {0.f, 0.f, 0.f, 0.f}, q = {0.f, 0.f, 0.f, 0.f};
    float4 mx = {-INFINITY, -INFINITY, -INFINITY, -INFINITY};
    float4 mn = {INFINITY, INFINITY, INFINITY, INFINITY};
    for (int r = r0; r < rEnd; r += 16) {
        half4v hv = *(const half4v*)(X + (size_t)r * C + c);
        float v0 = (float)hv[0], v1 = (float)hv[1], v2 = (float)hv[2], v3 = (float)hv[3];
        s.x += v0; s.y += v1; s.z += v2; s.w += v3;
        q.x = fmaf(v0, v0, q.x); q.y = fmaf(v1, v1, q.y);
        q.z = fmaf(v2, v2, q.z); q.w = fmaf(v3, v3, q.w);
        mx.x = fmaxf(mx.x, v0); mx.y = fmaxf(mx.y, v1);
        mx.z = fmaxf(mx.z, v2); mx.w = fmaxf(mx.w, v3);
        mn.x = fminf(mn.x, v0); mn.y = fminf(mn.y, v1);
        mn.z = fminf(mn.z, v2); mn.w = fminf(mn.w, v3);
    }
    sl[t][0] = s.x; sl[t][1] = s.y; sl[t][2] = s.z; sl[t][3] = s.w;
    ql[t][0] = q.x; ql[t][1] = q.y; ql[t][2] = q.z; ql[t][3] = q.w;
    xl[t][0] = mx.x; xl[t][1] = mx.y; xl[t][2] = mx.z; xl[t][3] = mx.w;
    nl[t][0] = mn.x; nl[t][1] = mn.y; nl[t][2] = mn.z; nl[t][3] = mn.w;
    __syncthreads();
    if (t < 64) {
        int comp = t & 3, grp = t >> 2;
        float ss = 0.f, qq = 0.f, xx = -INFINITY, nn = INFINITY;
#pragma unroll
        for (int g = 0; g < 16; ++g) {
            ss += sl[grp + (g << 4)][comp];
            qq += ql[grp + (g << 4)][comp];
            xx = fmaxf(xx, xl[grp + (g << 4)][comp]);
            nn = fminf(nn, nl[grp + (g << 4)][comp]);
        }
        size_t o = (size_t)blockIdx.y * C + (blockIdx.x << 6) + t;
        ps[o] = ss; pq[o] = qq; pmx[o] = xx; pmn[o] = nn;
    }
}

__global__ __launch_bounds__(64) void stats_fin_kernel(const float* __restrict__ ps,
                                                       const float* __restrict__ pq,
                                                       int C, float invM,
                                                       const float* __restrict__ g,
                                                       const float* __restrict__ bb,
                                                       float* __restrict__ scale,
                                                       float* __restrict__ shift)
{
    int c = blockIdx.x * 64 + threadIdx.x;
    float s = 0.f, q = 0.f;
    for (int ch = 0; ch < STAT_NCH; ++ch) { s += ps[(size_t)ch * C + c]; q += pq[(size_t)ch * C + c]; }
    float m  = s * invM;
    float v  = fmaxf(q * invM - m * m, 0.f);
    float sc = g[c] / sqrtf(v + EPSBN);
    scale[c] = sc;
    shift[c] = bb[c] - m * sc;
}

// ---------- gather + bn on the fly + max + relu, C=64 f32 raw -> f16 output
__global__ __launch_bounds__(256) void gmax1_kernel(const float* __restrict__ f,
                                                    const float* __restrict__ scale,
                                                    const float* __restrict__ shift,
                                                    const int* __restrict__ idx,
                                                    _Float16* __restrict__ agg)
{
    int bid = (blockIdx.x & 7) * 128 + (blockIdx.x >> 3);   // 1024 blocks, bijective
    int t = threadIdx.x;
    int sub = t >> 4;                       // 0..15 point-within-block
    int l16 = t & 15;                       // lane-group: 4 cols
    int p = bid * 16 + sub;
    int c = l16 << 2;
    int b = p >> 11;
    float4 sc = *(const float4*)(scale + c);
    float4 sh = *(const float4*)(shift + c);
    const int* ir = idx + (size_t)p * 16;
    const float* fb = f + ((size_t)(b << 11)) * 64;
    float4 m = {-INFINITY, -INFINITY, -INFINITY, -INFINITY};
#pragma unroll
    for (int k = 0; k < 16; ++k) {
        int nj = ir[k];
        float4 v = *(const float4*)(fb + (size_t)nj * 64 + c);
        m.x = fmaxf(m.x, fmaf(v.x, sc.x, sh.x));
        m.y = fmaxf(m.y, fmaf(v.y, sc.y, sh.y));
        m.z = fmaxf(m.z, fmaf(v.z, sc.z, sh.z));
        m.w = fmaxf(m.w, fmaf(v.w, sc.w, sh.w));
    }
    half4v o;
    o[0] = (_Float16)fmaxf(m.x, 0.f);
    o[1] = (_Float16)fmaxf(m.y, 0.f);
    o[2] = (_Float16)fmaxf(m.z, 0.f);
    o[3] = (_Float16)fmaxf(m.w, 0.f);
    *(half4v*)(agg + (size_t)p * 64 + c) = o;
}

// ------ gather(f16) + bn + max + relu, C=512 -> f16; 4 points/block
__global__ __launch_bounds__(256) void gmax2_kernel(const _Float16* __restrict__ f,
                                                    const float* __restrict__ scale,
                                                    const float* __restrict__ shift,
                                                    const int* __restrict__ idx,
                                                    _Float16* __restrict__ agg)
{
    int bid = (blockIdx.x & 7) * 512 + (blockIdx.x >> 3);   // 4096 blocks, bijective
    int t = threadIdx.x;
    int sub = t >> 6;                       // 0..3 point-within-block
    int lane = t & 63;                      // 8 cols per lane
    int p = bid * 4 + sub;
    int c = lane << 3;
    int b = p >> 11;
    float4 sc0 = *(const float4*)(scale + c);
    float4 sc1 = *(const float4*)(scale + c + 4);
    float4 sh0 = *(const float4*)(shift + c);
    float4 sh1 = *(const float4*)(shift + c + 4);
    const int* ir = idx + (size_t)p * 16;
    const _Float16* fb = f + ((size_t)(b << 11)) * 512;
    float m0 = -INFINITY, m1 = -INFINITY, m2 = -INFINITY, m3 = -INFINITY;
    float m4 = -INFINITY, m5 = -INFINITY, m6 = -INFINITY, m7 = -INFINITY;
#pragma unroll
    for (int k = 0; k < 16; ++k) {
        int nj = ir[k];
        half8 v = *(const half8*)(fb + (size_t)nj * 512 + c);
        m0 = fmaxf(m0, fmaf((float)v[0], sc0.x, sh0.x));
        m1 = fmaxf(m1, fmaf((float)v[1], sc0.y, sh0.y));
        m2 = fmaxf(m2, fmaf((float)v[2], sc0.z, sh0.z));
        m3 = fmaxf(m3, fmaf((float)v[3], sc0.w, sh0.w));
        m4 = fmaxf(m4, fmaf((float)v[4], sc1.x, sh1.x));
        m5 = fmaxf(m5, fmaf((float)v[5], sc1.y, sh1.y));
        m6 = fmaxf(m6, fmaf((float)v[6], sc1.z, sh1.z));
        m7 = fmaxf(m7, fmaf((float)v[7], sc1.w, sh1.w));
    }
    half8 o;
    o[0] = (_Float16)fmaxf(m0, 0.f); o[1] = (_Float16)fmaxf(m1, 0.f);
    o[2] = (_Float16)fmaxf(m2, 0.f); o[3] = (_Float16)fmaxf(m3, 0.f);
    o[4] = (_Float16)fmaxf(m4, 0.f); o[5] = (_Float16)fmaxf(m5, 0.f);
    o[6] = (_Float16)fmaxf(m6, 0.f); o[7] = (_Float16)fmaxf(m7, 0.f);
    *(half8*)(agg + (size_t)p * 512 + c) = o;
}

// ------- glob[b][c]: inline BN-stat finalize + chunk max/min + affine (exact)
__global__ __launch_bounds__(256) void globred2_kernel(const float* __restrict__ pmx,
                                                       const float* __restrict__ pmn,
                                                       const float* __restrict__ ps,
                                                       const float* __restrict__ pq,
                                                       const float* __restrict__ g,
                                                       const float* __restrict__ bb,
                                                       float* __restrict__ glob)
{
    int c = blockIdx.x * 256 + threadIdx.x;
    int b = blockIdx.y;
    float s = 0.f, q = 0.f;
    for (int ch = 0; ch < STAT_NCH; ++ch) { s += ps[(size_t)ch * 1024 + c]; q += pq[(size_t)ch * 1024 + c]; }
    const float invM = 1.0f / 16384.0f;
    float m  = s * invM;
    float v  = fmaxf(q * invM - m * m, 0.f);
    float sc = g[c] / sqrtf(v + EPSBN);
    float sh = bb[c] - m * sc;
    float mx = -INFINITY, mn = INFINITY;
#pragma unroll
    for (int ch = 0; ch < 16; ++ch) {
        size_t o = (size_t)(b * 16 + ch) * 1024 + c;
        mx = fmaxf(mx, pmx[o]);
        mn = fminf(mn, pmn[o]);
    }
    float vv = (sc >= 0.f) ? mx : mn;
    glob[(size_t)b * 1024 + c] = fmaf(sc, vv, sh);
}

// ------------- final (8x1024)@(1024x512) + BN(8), 64 blocks (col x K split)
__global__ __launch_bounds__(256) void final_kernel(const float* __restrict__ glob,
                                                    const float* __restrict__ w2,
                                                    const float* __restrict__ g,
                                                    const float* __restrict__ bb,
                                                    float* __restrict__ out)
{
    __shared__ float partial[8][8][4];
    __shared__ float vals[8][8];
    int t = threadIdx.x;
    int c8 = blockIdx.x << 3;              // 8 cols per block
    int r = t >> 5, c = (t >> 2) & 7, kq = t & 3;
    const float* gr = glob + (size_t)r * 1024 + (kq << 8);
    const float* wc = w2 + ((size_t)(kq << 8)) * 512 + c8 + c;
    float a = 0.f;
    for (int k = 0; k < 256; ++k)
        a = fmaf(gr[k], wc[(size_t)k * 512], a);
    partial[r][c][kq] = a;
    __syncthreads();
    if (t < 64) {
        int rr = t >> 3, cc = t & 7;
        vals[rr][cc] = partial[rr][cc][0] + partial[rr][cc][1]
                     + partial[rr][cc][2] + partial[rr][cc][3];
    }
    __syncthreads();
    if (t < 8) {
        int cc = t, cg = c8 + t;
        float s = 0.f;
#pragma unroll
        for (int rr = 0; rr < 8; ++rr) s += vals[rr][cc];
        float m = s * 0.125f;
        float v = 0.f;
#pragma unroll
        for (int rr = 0; rr < 8; ++rr) { float d = vals[rr][cc] - m; v = fmaf(d, d, v); }
        v *= 0.125f;
        float sc = g[cg] / sqrtf(v + EPSBN);
#pragma unroll
        for (int rr = 0; rr < 8; ++rr)
            out[(size_t)rr * 512 + cg] = fmaf(vals[rr][cc] - m, sc, bb[cg]);
    }
}

// =============================================================== launch
extern "C" void kernel_launch(void* const* d_in, const int* in_sizes, int n_in,
                              void* d_out, int out_size, void* d_ws, size_t ws_size,
                              hipStream_t stream)
{
    const float* x   = (const float*)d_in[0];
    const float* w1a = (const float*)d_in[1];
    const float* g1a = (const float*)d_in[2];
    const float* b1a = (const float*)d_in[3];
    const float* w1b = (const float*)d_in[4];
    const float* g1b = (const float*)d_in[5];
    const float* b1b = (const float*)d_in[6];
    const float* w1c = (const float*)d_in[7];
    const float* g1c = (const float*)d_in[8];
    const float* b1c = (const float*)d_in[9];
    const float* wg1 = (const float*)d_in[10];
    const float* gg1 = (const float*)d_in[11];
    const float* bg1 = (const float*)d_in[12];
    const float* wg2 = (const float*)d_in[13];
    const float* gg2 = (const float*)d_in[14];
    const float* bg2 = (const float*)d_in[15];
    const float* w2  = (const float*)d_in[16];
    const float* g2  = (const float*)d_in[17];
    const float* b2  = (const float*)d_in[18];

    char* w = (char*)d_ws;
    size_t off = 0;
    auto take = [&](size_t bytes) -> char* {
        char* p = w + off;
        off += (bytes + 255) & ~(size_t)255;
        return p;
    };
    int*       idx     = (int*)      take((size_t)16384 * 16 * 4);
    float*     h0      = (float*)    take((size_t)16384 * 64 * 4);
    float*     h1      = (float*)    take((size_t)16384 * 64 * 4);
    float*     h2      = (float*)    take((size_t)16384 * 64 * 4);
    _Float16*  f512h   = (_Float16*) take((size_t)16384 * 512 * 2);
    _Float16*  f1024h  = (_Float16*) take((size_t)16384 * 1024 * 2);
    _Float16*  aggh64  = (_Float16*) take((size_t)16384 * 64 * 2);
    _Float16*  agg512h = (_Float16*) take((size_t)16384 * 512 * 2);
    _Float16*  w1T     = (_Float16*) take((size_t)512 * 64 * 2);
    _Float16*  w2T     = (_Float16*) take((size_t)1024 * 512 * 2);
    float*     ps      = (float*)    take((size_t)STAT_NCH * 1024 * 4);
    float*     pq      = (float*)    take((size_t)STAT_NCH * 1024 * 4);
    float*     pmx     = (float*)    take((size_t)STAT_NCH * 1024 * 4);
    float*     pmn     = (float*)    take((size_t)STAT_NCH * 1024 * 4);
    float* scA  = (float*)take(64 * 4);   float* shA  = (float*)take(64 * 4);
    float* scB  = (float*)take(64 * 4);   float* shB  = (float*)take(64 * 4);
    float* scC  = (float*)take(64 * 4);   float* shC  = (float*)take(64 * 4);
    float* scG1 = (float*)take(512 * 4);  float* shG1 = (float*)take(512 * 4);
    float* glob = (float*)take((size_t)8 * 1024 * 4);
    (void)ws_size; (void)in_sizes; (void)n_in; (void)out_size;

    const float invM = 1.0f / 16384.0f;

    // merged weight conversion + knn up front
    wtrans2_kernel<<<(64 * 512 + 512 * 1024) / 256, 256, 0, stream>>>(wg1, wg2, w1T, w2T);
    knn_kernel<<<512, 512, 0, stream>>>(x, idx);

    // fused covariance-feature + 19->64 linear (h0 raw) + stats
    cov_lin_kernel<<<256, 256, 0, stream>>>(x, idx, w1a, h0);
    stats_part_kernel<<<dim3(1, STAT_NCH), 256, 0, stream>>>(h0, 64, ps, pq);
    stats_fin_kernel<<<1, 64, 0, stream>>>(ps, pq, 64, invM, g1a, b1a, scA, shA);

    // L1b: bn_relu(h0) @ w1b -> h1 raw, stats on h1
    gemm_bn_kernel<<<dim3(1, 256), 256, 0, stream>>>(h0, w1b, h1, scA, shA, 16384, 64, 64);
    stats_part_kernel<<<dim3(1, STAT_NCH), 256, 0, stream>>>(h1, 64, ps, pq);
    stats_fin_kernel<<<1, 64, 0, stream>>>(ps, pq, 64, invM, g1b, b1b, scB, shB);

    // L1c: bn_relu(h1) @ w1c -> h2 raw, stats on h2
    gemm_bn_kernel<<<dim3(1, 256), 256, 0, stream>>>(h1, w1c, h2, scB, shB, 16384, 64, 64);
    stats_part_kernel<<<dim3(1, STAT_NCH), 256, 0, stream>>>(h2, 64, ps, pq);
    stats_fin_kernel<<<1, 64, 0, stream>>>(ps, pq, 64, invM, g1c, b1c, scC, shC);

    // graph pool 1: gather(bn(h2))-max-relu(f16) then f16 MFMA 64->512 (f16 out)
    gmax1_kernel<<<1024, 256, 0, stream>>>(h2, scC, shC, idx, aggh64);
    hgemm_kernel<<<dim3(4, 128), 256, 0, stream>>>(aggh64, w1T, f512h, 16384, 512, 64);
    stats_part_h_kernel<<<dim3(8, STAT_NCH), 256, 0, stream>>>(f512h, 512, ps, pq);
    stats_fin_kernel<<<8, 64, 0, stream>>>(ps, pq, 512, invM, gg1, bg1, scG1, shG1);

    // graph pool 2: gather(bn)-max-relu(f16) then f16 MFMA 512->1024 (f16 out)
    gmax2_kernel<<<4096, 256, 0, stream>>>(f512h, scG1, shG1, idx, agg512h);
    hgemm_kernel<<<dim3(8, 128), 256, 0, stream>>>(agg512h, w2T, f1024h, 16384, 1024, 512);
    stats_minmax_part_h_kernel<<<dim3(16, STAT_NCH), 256, 0, stream>>>(f1024h, 1024, ps, pq, pmx, pmn);

    // global max via per-chunk raw max/min + inline BN finalize (exact)
    globred2_kernel<<<dim3(4, 8), 256, 0, stream>>>(pmx, pmn, ps, pq, gg2, bg2, glob);

    // final linear + BN over 8 rows (64 blocks, K-split)
    final_kernel<<<64, 256, 0, stream>>>(glob, w2, g2, b2, (float*)d_out);
}

// Round 18
// 302.114 us; speedup vs baseline: 1.0515x; 1.0515x over previous
//
#include <hip/hip_runtime.h>
#include <math.h>

#define EPSBN 1e-5f
#define STAT_NCH 128

typedef _Float16 half8 __attribute__((ext_vector_type(8)));
typedef _Float16 half4v __attribute__((ext_vector_type(4)));
typedef float floatx4 __attribute__((ext_vector_type(4)));
typedef unsigned int uint32;

// ------------------------------------------------ KNN (top-16), 8-way chunked
// R16-exact: 256 blocks x 512 thr, 8 chunks of 256 cand, 76 KB LDS, VGPR ~52.
// Measured 108.6 us. Five occupancy experiments (R5/R7/R8/R15/R17) all lost
// to this config — LOCKED.
__global__ __launch_bounds__(512) void knn_kernel(const float* __restrict__ x,
                                                  int* __restrict__ idx)
{
    __shared__ float  xs[2048], ys[2048], sq[2048];   // 24 KB
    __shared__ float  md[8][64][17];                  // 34.8 KB
    __shared__ ushort mi[8][64][18];                  // 18.4 KB -> 76 KB total
    int b  = blockIdx.x >> 5;              // 32 blocks per batch
    int q0 = (blockIdx.x & 31) << 6;       // 64 queries per block
    const float* xb = x + (size_t)b * 2048 * 10;
    for (int j = threadIdx.x; j < 2048; j += 512) {
        float xj = xb[j * 10 + 0], yj = xb[j * 10 + 1];
        xs[j] = xj; ys[j] = yj;
        sq[j] = __fadd_rn(__fmul_rn(xj, xj), __fmul_rn(yj, yj));
    }
    __syncthreads();
    int lane = threadIdx.x & 63;
    int chunk = threadIdx.x >> 6;          // 0..7
    int i = q0 + lane;                     // query index within batch
    float xi = xs[i], yi = ys[i], sqi = sq[i];
    float bd[16]; int bi[16];
#pragma unroll
    for (int s = 0; s < 16; ++s) { bd[s] = INFINITY; bi[s] = 0; }
    int j0 = chunk << 8;
    for (int jj = 0; jj < 256; ++jj) {
        int j = j0 + jj;
        float dot = __fadd_rn(__fmul_rn(xi, xs[j]), __fmul_rn(yi, ys[j]));
        float d   = __fsub_rn(__fadd_rn(sqi, sq[j]), __fmul_rn(2.0f, dot));
        if (j == i) d = INFINITY;
        if (d < bd[15]) {                  // strict < : ties keep lower index
            bd[15] = d; bi[15] = j;
#pragma unroll
            for (int s = 15; s > 0; --s) {
                if (bd[s] < bd[s - 1]) {
                    float td = bd[s]; bd[s] = bd[s - 1]; bd[s - 1] = td;
                    int   ti = bi[s]; bi[s] = bi[s - 1]; bi[s - 1] = ti;
                }
            }
        }
    }
#pragma unroll
    for (int s = 0; s < 16; ++s) { md[chunk][lane][s] = bd[s]; mi[chunk][lane][s] = (ushort)bi[s]; }
    __syncthreads();
    if (threadIdx.x < 64) {
        int q = threadIdx.x;
        float fd[16]; int fi[16];
#pragma unroll
        for (int s = 0; s < 16; ++s) { fd[s] = INFINITY; fi[s] = 0; }
        for (int c = 0; c < 8; ++c) {
            for (int s = 0; s < 16; ++s) {
                float d = md[c][q][s];
                if (!(d < fd[15])) break;  // sorted list: rest can't qualify
                int j = (int)mi[c][q][s];
                fd[15] = d; fi[15] = j;
#pragma unroll
                for (int t = 15; t > 0; --t) {
                    if (fd[t] < fd[t - 1]) {
                        float td = fd[t]; fd[t] = fd[t - 1]; fd[t - 1] = td;
                        int   ti = fi[t]; fi[t] = fi[t - 1]; fi[t - 1] = ti;
                    }
                }
            }
        }
        int* out = idx + (size_t)(b * 2048 + q0 + q) * 16;
#pragma unroll
        for (int s = 0; s < 16; ++s) out[s] = fi[s];
    }
}

// ---- fused covariance + 19-ch feature + 19->64 linear (4 threads/point)
__global__ __launch_bounds__(256) void cov_lin_kernel(const float* __restrict__ x,
                                                      const int* __restrict__ idx,
                                                      const float* __restrict__ w1a,
                                                      float* __restrict__ h0)
{
    __shared__ float ws_[19 * 64];
    for (int i = threadIdx.x; i < 19 * 64; i += 256) ws_[i] = w1a[i];
    __syncthreads();
    int gid = blockIdx.x * 256 + threadIdx.x;   // 0..65535
    int p   = gid >> 2;                          // point 0..16383
    int sub = gid & 3;
    int b   = p >> 11;
    const float* xb = x + ((size_t)(b << 11)) * 10;
    const int* ir = idx + (size_t)p * 16 + sub * 4;
    float sx = 0.f, sy = 0.f, se = 0.f;
    float sxx = 0.f, sxy = 0.f, sxe = 0.f;
    float syy = 0.f, sye = 0.f, see = 0.f;
#pragma unroll
    for (int k = 0; k < 4; ++k) {
        int nj = ir[k];
        const float* nr = xb + (size_t)nj * 10;
        float nx = nr[0], ny = nr[1];
        float ne = nr[2] + nr[3] + nr[4] + nr[5] + nr[6] + nr[7] + nr[8] + nr[9];
        sx += nx; sy += ny; se += ne;
        sxx += nx * nx; sxy += nx * ny; sxe += nx * ne;
        syy += ny * ny; sye += ny * ne; see += ne * ne;
    }
    const float* xr = x + (size_t)p * 10;
    float v0 = xr[0], v1 = xr[1], v2 = xr[2], v3 = xr[3], v4 = xr[4];
    float v5 = xr[5], v6 = xr[6], v7 = xr[7], v8 = xr[8], v9 = xr[9];
    float ec = v2 + v3 + v4 + v5 + v6 + v7 + v8 + v9;
    if (sub == 0) {
        sx += v0; sy += v1; se += ec;
        sxx += v0 * v0; sxy += v0 * v1; sxe += v0 * ec;
        syy += v1 * v1; sye += v1 * ec; see += ec * ec;
    }
    sx  += __shfl_xor(sx, 1);  sx  += __shfl_xor(sx, 2);
    sy  += __shfl_xor(sy, 1);  sy  += __shfl_xor(sy, 2);
    se  += __shfl_xor(se, 1);  se  += __shfl_xor(se, 2);
    sxx += __shfl_xor(sxx, 1); sxx += __shfl_xor(sxx, 2);
    sxy += __shfl_xor(sxy, 1); sxy += __shfl_xor(sxy, 2);
    sxe += __shfl_xor(sxe, 1); sxe += __shfl_xor(sxe, 2);
    syy += __shfl_xor(syy, 1); syy += __shfl_xor(syy, 2);
    sye += __shfl_xor(sye, 1); sye += __shfl_xor(sye, 2);
    see += __shfl_xor(see, 1); see += __shfl_xor(see, 2);
    const float inv = 1.0f / 17.0f;
    float mx = sx * inv, my = sy * inv, me = se * inv;
    float f[19];
    f[0] = v0; f[1] = v1; f[2] = v2; f[3] = v3; f[4] = v4;
    f[5] = v5; f[6] = v6; f[7] = v7; f[8] = v8; f[9] = v9;
    f[10] = sxx * inv - mx * mx; f[11] = sxy * inv - mx * my; f[12] = sxe * inv - mx * me;
    f[13] = f[11];               f[14] = syy * inv - my * my; f[15] = sye * inv - my * me;
    f[16] = f[12];               f[17] = f[15];               f[18] = see * inv - me * me;
    int c0 = sub << 4;
    float acc[16];
#pragma unroll
    for (int j = 0; j < 16; ++j) acc[j] = 0.f;
#pragma unroll
    for (int k = 0; k < 19; ++k) {
        float fv = f[k];
        const float* wr = &ws_[k * 64 + c0];
#pragma unroll
        for (int j = 0; j < 16; ++j) acc[j] = fmaf(fv, wr[j], acc[j]);
    }
    float* o = h0 + (size_t)p * 64 + c0;
#pragma unroll
    for (int j = 0; j < 16; j += 4) {
        float4 ov = {acc[j], acc[j + 1], acc[j + 2], acc[j + 3]};
        *(float4*)(o + j) = ov;
    }
}

// ---------------- fp32 tiled GEMM with fused input BN+ReLU on the A-load
__global__ __launch_bounds__(256) void gemm_bn_kernel(const float* __restrict__ A,
                                                      const float* __restrict__ B,
                                                      float* __restrict__ C,
                                                      const float* __restrict__ asc,
                                                      const float* __restrict__ ash,
                                                      int M, int N, int K)
{
    __shared__ float As[16][64];   // [k][row]
    __shared__ float Bs[16][64];   // [k][col]
    __shared__ float ssc[64], ssh[64];
    int t  = threadIdx.x;
    if (t < 64) { ssc[t] = asc[t]; ssh[t] = ash[t]; }
    int m0 = blockIdx.y << 6, n0 = blockIdx.x << 6;
    int arow = t >> 2, acol = (t & 3) << 2;
    int brow = t >> 4, bcol = (t & 15) << 2;
    int tr = (t >> 4) << 2, tc = (t & 15) << 2;
    float acc[4][4] = {};
    for (int k0 = 0; k0 < K; k0 += 16) {
        float4 av = *(const float4*)(A + (size_t)(m0 + arow) * K + k0 + acol);
        float4 bv = *(const float4*)(B + (size_t)(k0 + brow) * N + n0 + bcol);
        __syncthreads();
        int ka = k0 + acol;
        As[acol + 0][arow] = fmaxf(fmaf(av.x, ssc[ka + 0], ssh[ka + 0]), 0.f);
        As[acol + 1][arow] = fmaxf(fmaf(av.y, ssc[ka + 1], ssh[ka + 1]), 0.f);
        As[acol + 2][arow] = fmaxf(fmaf(av.z, ssc[ka + 2], ssh[ka + 2]), 0.f);
        As[acol + 3][arow] = fmaxf(fmaf(av.w, ssc[ka + 3], ssh[ka + 3]), 0.f);
        *(float4*)&Bs[brow][bcol] = bv;
        __syncthreads();
#pragma unroll
        for (int kk = 0; kk < 16; ++kk) {
            float4 a = *(const float4*)&As[kk][tr];
            float4 bb = *(const float4*)&Bs[kk][tc];
            float ar[4] = {a.x, a.y, a.z, a.w};
            float br[4] = {bb.x, bb.y, bb.z, bb.w};
#pragma unroll
            for (int i = 0; i < 4; ++i)
#pragma unroll
                for (int j = 0; j < 4; ++j)
                    acc[i][j] = fmaf(ar[i], br[j], acc[i][j]);
        }
    }
#pragma unroll
    for (int i = 0; i < 4; ++i) {
        float4 o;
        o.x = acc[i][0]; o.y = acc[i][1]; o.z = acc[i][2]; o.w = acc[i][3];
        *(float4*)(C + (size_t)(m0 + tr + i) * N + n0 + tc) = o;
    }
}

// ------------- fp16 MFMA GEMM, 128x128 tile, async global_load_lds staging
__global__ __launch_bounds__(256) void hgemm_kernel(const _Float16* __restrict__ A,
                                                    const _Float16* __restrict__ BT,
                                                    _Float16* __restrict__ C,
                                                    int M, int N, int K)
{
    __shared__ __align__(16) _Float16 As[2][4][128][8];
    __shared__ __align__(16) _Float16 Bs[2][4][128][8];
    int t = threadIdx.x;
    int m0 = blockIdx.y << 7, n0 = blockIdx.x << 7;
    int wv = t >> 6, lane = t & 63;
    int fr = lane & 15, fk = lane >> 4;
    int srow = t & 63, sk8 = t >> 6;
    const _Float16* Ab = A + (size_t)m0 * K + sk8 * 8;
    const _Float16* Bb = BT + (size_t)n0 * K + sk8 * 8;

    floatx4 zero = {0.f, 0.f, 0.f, 0.f};
    floatx4 acc[2][8];
#pragma unroll
    for (int i = 0; i < 2; ++i)
#pragma unroll
        for (int j = 0; j < 8; ++j) acc[i][j] = zero;

    int NC = K >> 5;

#define HG_STAGE(bf, kc)                                                                        \
    do {                                                                                        \
        int kb_ = (kc) << 5;                                                                    \
        __builtin_amdgcn_global_load_lds(                                                       \
            (const __attribute__((address_space(1))) uint32*)(Ab + (size_t)srow * K + kb_),     \
            (__attribute__((address_space(3))) uint32*)&As[bf][sk8][srow][0], 16, 0, 0);        \
        __builtin_amdgcn_global_load_lds(                                                       \
            (const __attribute__((address_space(1))) uint32*)(Ab + (size_t)(srow + 64) * K + kb_),\
            (__attribute__((address_space(3))) uint32*)&As[bf][sk8][srow + 64][0], 16, 0, 0);   \
        __builtin_amdgcn_global_load_lds(                                                       \
            (const __attribute__((address_space(1))) uint32*)(Bb + (size_t)srow * K + kb_),     \
            (__attribute__((address_space(3))) uint32*)&Bs[bf][sk8][srow][0], 16, 0, 0);        \
        __builtin_amdgcn_global_load_lds(                                                       \
            (const __attribute__((address_space(1))) uint32*)(Bb + (size_t)(srow + 64) * K + kb_),\
            (__attribute__((address_space(3))) uint32*)&Bs[bf][sk8][srow + 64][0], 16, 0, 0);   \
    } while (0)

    HG_STAGE(0, 0);
    __syncthreads();

    for (int kc = 0; kc < NC; ++kc) {
        int cur = kc & 1;
        if (kc + 1 < NC) HG_STAGE(cur ^ 1, kc + 1);
        half8 af[2];
#pragma unroll
        for (int mg = 0; mg < 2; ++mg)
            af[mg] = *(const half8*)&As[cur][fk][(wv << 5) + (mg << 4) + fr][0];
#pragma unroll
        for (int ng = 0; ng < 8; ++ng) {
            half8 bf = *(const half8*)&Bs[cur][fk][(ng << 4) + fr][0];
            acc[0][ng] = __builtin_amdgcn_mfma_f32_16x16x32_f16(af[0], bf, acc[0][ng], 0, 0, 0);
            acc[1][ng] = __builtin_amdgcn_mfma_f32_16x16x32_f16(af[1], bf, acc[1][ng], 0, 0, 0);
        }
        __syncthreads();
    }
#undef HG_STAGE
    int orow = m0 + (wv << 5) + (fk << 2);
#pragma unroll
    for (int mg = 0; mg < 2; ++mg)
#pragma unroll
        for (int ng = 0; ng < 8; ++ng)
#pragma unroll
            for (int i = 0; i < 4; ++i)
                C[(size_t)(orow + (mg << 4) + i) * N + n0 + (ng << 4) + fr] =
                    (_Float16)acc[mg][ng][i];
}

// ---------------- merged weight transpose+convert for both weights
__global__ __launch_bounds__(256) void wtrans2_kernel(const float* __restrict__ wa,
                                                      const float* __restrict__ wb,
                                                      _Float16* __restrict__ waT,
                                                      _Float16* __restrict__ wbT)
{
    int id = blockIdx.x * 256 + threadIdx.x;
    if (id < 64 * 512) {
        int k = id >> 9, n = id & 511;
        waT[(size_t)n * 64 + k] = (_Float16)wa[id];
    } else {
        int id2 = id - 64 * 512;
        int k = id2 >> 10, n = id2 & 1023;
        wbT[(size_t)n * 512 + k] = (_Float16)wb[id2];
    }
}

// --------------------------------------------------- BN stats (f32 input)
__global__ __launch_bounds__(256) void stats_part_kernel(const float* __restrict__ X,
                                                         int C,
                                                         float* __restrict__ ps,
                                                         float* __restrict__ pq)
{
    __shared__ float sl[256][4];
    __shared__ float ql[256][4];
    int t = threadIdx.x;
    int c = (blockIdx.x << 6) + ((t & 15) << 2);
    int rowsPer = 16384 / STAT_NCH;
    int r0 = blockIdx.y * rowsPer + (t >> 4);
    int rEnd = blockIdx.y * rowsPer + rowsPer;
    float4 s = {0.f, 0.f, 0.f, 0.f}, q = {0.f, 0.f, 0.f, 0.f};
    for (int r = r0; r < rEnd; r += 16) {
        float4 v = *(const float4*)(X + (size_t)r * C + c);
        s.x += v.x; s.y += v.y; s.z += v.z; s.w += v.w;
        q.x = fmaf(v.x, v.x, q.x); q.y = fmaf(v.y, v.y, q.y);
        q.z = fmaf(v.z, v.z, q.z); q.w = fmaf(v.w, v.w, q.w);
    }
    sl[t][0] = s.x; sl[t][1] = s.y; sl[t][2] = s.z; sl[t][3] = s.w;
    ql[t][0] = q.x; ql[t][1] = q.y; ql[t][2] = q.z; ql[t][3] = q.w;
    __syncthreads();
    if (t < 64) {
        int comp = t & 3, grp = t >> 2;
        float ss = 0.f, qq = 0.f;
#pragma unroll
        for (int g = 0; g < 16; ++g) {
            ss += sl[grp + (g << 4)][comp];
            qq += ql[grp + (g << 4)][comp];
        }
        ps[(size_t)blockIdx.y * C + (blockIdx.x << 6) + t] = ss;
        pq[(size_t)blockIdx.y * C + (blockIdx.x << 6) + t] = qq;
    }
}

// --------------------------------------------------- BN stats (f16 input)
__global__ __launch_bounds__(256) void stats_part_h_kernel(const _Float16* __restrict__ X,
                                                           int C,
                                                           float* __restrict__ ps,
                                                           float* __restrict__ pq)
{
    __shared__ float sl[256][4];
    __shared__ float ql[256][4];
    int t = threadIdx.x;
    int c = (blockIdx.x << 6) + ((t & 15) << 2);
    int rowsPer = 16384 / STAT_NCH;
    int r0 = blockIdx.y * rowsPer + (t >> 4);
    int rEnd = blockIdx.y * rowsPer + rowsPer;
    float4 s = {0.f, 0.f, 0.f, 0.f}, q = {0.f, 0.f, 0.f, 0.f};
    for (int r = r0; r < rEnd; r += 16) {
        half4v hv = *(const half4v*)(X + (size_t)r * C + c);
        float v0 = (float)hv[0], v1 = (float)hv[1], v2 = (float)hv[2], v3 = (float)hv[3];
        s.x += v0; s.y += v1; s.z += v2; s.w += v3;
        q.x = fmaf(v0, v0, q.x); q.y = fmaf(v1, v1, q.y);
        q.z = fmaf(v2, v2, q.z); q.w = fmaf(v3, v3, q.w);
    }
    sl[t][0] = s.x; sl[t][1] = s.y; sl[t][2] = s.z; sl[t][3] = s.w;
    ql[t][0] = q.x; ql[t][1] = q.y; ql[t][2] = q.z; ql[t][3] = q.w;
    __syncthreads();
    if (t < 64) {
        int comp = t & 3, grp = t >> 2;
        float ss = 0.f, qq = 0.f;
#pragma unroll
        for (int g = 0; g < 16; ++g) {
            ss += sl[grp + (g << 4)][comp];
            qq += ql[grp + (g << 4)][comp];
        }
        ps[(size_t)blockIdx.y * C + (blockIdx.x << 6) + t] = ss;
        pq[(size_t)blockIdx.y * C + (blockIdx.x << 6) + t] = qq;
    }
}

// ------------- BN stats + per-chunk raw max/min (f16 input, for f1024 path)
__global__ __launch_bounds__(256) void stats_minmax_part_h_kernel(const _Float16* __restrict__ X,
                                                                  int C,
                                                                  float* __restrict__ ps,
                                                                  float* __restrict__ pq,
                                                                  float* __restrict__ pmx,
                                                                  float* __restrict__ pmn)
{
    __shared__ float sl[256][4];
    __shared__ float ql[256][4];
    __shared__ float xl[256][4];
    __shared__ float nl[256][4];
    int t = threadIdx.x;
    int c = (blockIdx.x << 6) + ((t & 15) << 2);
    int rowsPer = 16384 / STAT_NCH;
    int r0 = blockIdx.y * rowsPer + (t >> 4);
    int rEnd = blockIdx.y * rowsPer + rowsPer;
    float4 s = {0.f, 0.f, 0.f, 0.f}, q = {0.f, 0.f, 0.f, 0.f};
    float4 mx = {-INFINITY, -INFINITY, -INFINITY, -INFINITY};
    float4 mn = {INFINITY, INFINITY, INFINITY, INFINITY};
    for (int r = r0; r < rEnd; r += 16) {
        half4v hv = *(const half4v*)(X + (size_t)r * C + c);
        float v0 = (float)hv[0], v1 = (float)hv[1], v2 = (float)hv[2], v3 = (float)hv[3];
        s.x += v0; s.y += v1; s.z += v2; s.w += v3;
        q.x = fmaf(v0, v0, q.x); q.y = fmaf(v1, v1, q.y);
        q.z = fmaf(v2, v2, q.z); q.w = fmaf(v3, v3, q.w);
        mx.x = fmaxf(mx.x, v0); mx.y = fmaxf(mx.y, v1);
        mx.z = fmaxf(mx.z, v2); mx.w = fmaxf(mx.w, v3);
        mn.x = fminf(mn.x, v0); mn.y = fminf(mn.y, v1);
        mn.z = fminf(mn.z, v2); mn.w = fminf(mn.w, v3);
    }
    sl[t][0] = s.x; sl[t][1] = s.y; sl[t][2] = s.z; sl[t][3] = s.w;
    ql[t][0] = q.x; ql[t][1] = q.y; ql[t][2] = q.z; ql[t][3] = q.w;
    xl[t][0] = mx.x; xl[t][1] = mx.y; xl[t][2] = mx.z; xl[t][3] = mx.w;
    nl[t][0] = mn.x; nl[t][1] = mn.y; nl[t][2] = mn.z; nl[t][3] = mn.w;
    __syncthreads();
    if (t < 64) {
        int comp = t & 3, grp = t >> 2;
        float ss = 0.f, qq = 0.f, xx = -INFINITY, nn = INFINITY;
#pragma unroll
        for (int g = 0; g < 16; ++g) {
            ss += sl[grp + (g << 4)][comp];
            qq += ql[grp + (g << 4)][comp];
            xx = fmaxf(xx, xl[grp + (g << 4)][comp]);
            nn = fminf(nn, nl[grp + (g << 4)][comp]);
        }
        size_t o = (size_t)blockIdx.y * C + (blockIdx.x << 6) + t;
        ps[o] = ss; pq[o] = qq; pmx[o] = xx; pmn[o] = nn;
    }
}

__global__ __launch_bounds__(64) void stats_fin_kernel(const float* __restrict__ ps,
                                                       const float* __restrict__ pq,
                                                       int C, float invM,
                                                       const float* __restrict__ g,
                                                       const float* __restrict__ bb,
                                                       float* __restrict__ scale,
                                                       float* __restrict__ shift)
{
    int c = blockIdx.x * 64 + threadIdx.x;
    float s = 0.f, q = 0.f;
    for (int ch = 0; ch < STAT_NCH; ++ch) { s += ps[(size_t)ch * C + c]; q += pq[(size_t)ch * C + c]; }
    float m  = s * invM;
    float v  = fmaxf(q * invM - m * m, 0.f);
    float sc = g[c] / sqrtf(v + EPSBN);
    scale[c] = sc;
    shift[c] = bb[c] - m * sc;
}

// ---------- gather + bn on the fly + max + relu, C=64 f32 raw -> f16 output
__global__ __launch_bounds__(256) void gmax1_kernel(const float* __restrict__ f,
                                                    const float* __restrict__ scale,
                                                    const float* __restrict__ shift,
                                                    const int* __restrict__ idx,
                                                    _Float16* __restrict__ agg)
{
    int bid = (blockIdx.x & 7) * 128 + (blockIdx.x >> 3);   // 1024 blocks, bijective
    int t = threadIdx.x;
    int sub = t >> 4;                       // 0..15 point-within-block
    int l16 = t & 15;                       // lane-group: 4 cols
    int p = bid * 16 + sub;
    int c = l16 << 2;
    int b = p >> 11;
    float4 sc = *(const float4*)(scale + c);
    float4 sh = *(const float4*)(shift + c);
    const int* ir = idx + (size_t)p * 16;
    const float* fb = f + ((size_t)(b << 11)) * 64;
    float4 m = {-INFINITY, -INFINITY, -INFINITY, -INFINITY};
#pragma unroll
    for (int k = 0; k < 16; ++k) {
        int nj = ir[k];
        float4 v = *(const float4*)(fb + (size_t)nj * 64 + c);
        m.x = fmaxf(m.x, fmaf(v.x, sc.x, sh.x));
        m.y = fmaxf(m.y, fmaf(v.y, sc.y, sh.y));
        m.z = fmaxf(m.z, fmaf(v.z, sc.z, sh.z));
        m.w = fmaxf(m.w, fmaf(v.w, sc.w, sh.w));
    }
    half4v o;
    o[0] = (_Float16)fmaxf(m.x, 0.f);
    o[1] = (_Float16)fmaxf(m.y, 0.f);
    o[2] = (_Float16)fmaxf(m.z, 0.f);
    o[3] = (_Float16)fmaxf(m.w, 0.f);
    *(half4v*)(agg + (size_t)p * 64 + c) = o;
}

// ------ gather(f16) + bn + max + relu, C=512 -> f16; 4 points/block
__global__ __launch_bounds__(256) void gmax2_kernel(const _Float16* __restrict__ f,
                                                    const float* __restrict__ scale,
                                                    const float* __restrict__ shift,
                                                    const int* __restrict__ idx,
                                                    _Float16* __restrict__ agg)
{
    int bid = (blockIdx.x & 7) * 512 + (blockIdx.x >> 3);   // 4096 blocks, bijective
    int t = threadIdx.x;
    int sub = t >> 6;                       // 0..3 point-within-block
    int lane = t & 63;                      // 8 cols per lane
    int p = bid * 4 + sub;
    int c = lane << 3;
    int b = p >> 11;
    float4 sc0 = *(const float4*)(scale + c);
    float4 sc1 = *(const float4*)(scale + c + 4);
    float4 sh0 = *(const float4*)(shift + c);
    float4 sh1 = *(const float4*)(shift + c + 4);
    const int* ir = idx + (size_t)p * 16;
    const _Float16* fb = f + ((size_t)(b << 11)) * 512;
    float m0 = -INFINITY, m1 = -INFINITY, m2 = -INFINITY, m3 = -INFINITY;
    float m4 = -INFINITY, m5 = -INFINITY, m6 = -INFINITY, m7 = -INFINITY;
#pragma unroll
    for (int k = 0; k < 16; ++k) {
        int nj = ir[k];
        half8 v = *(const half8*)(fb + (size_t)nj * 512 + c);
        m0 = fmaxf(m0, fmaf((float)v[0], sc0.x, sh0.x));
        m1 = fmaxf(m1, fmaf((float)v[1], sc0.y, sh0.y));
        m2 = fmaxf(m2, fmaf((float)v[2], sc0.z, sh0.z));
        m3 = fmaxf(m3, fmaf((float)v[3], sc0.w, sh0.w));
        m4 = fmaxf(m4, fmaf((float)v[4], sc1.x, sh1.x));
        m5 = fmaxf(m5, fmaf((float)v[5], sc1.y, sh1.y));
        m6 = fmaxf(m6, fmaf((float)v[6], sc1.z, sh1.z));
        m7 = fmaxf(m7, fmaf((float)v[7], sc1.w, sh1.w));
    }
    half8 o;
    o[0] = (_Float16)fmaxf(m0, 0.f); o[1] = (_Float16)fmaxf(m1, 0.f);
    o[2] = (_Float16)fmaxf(m2, 0.f); o[3] = (_Float16)fmaxf(m3, 0.f);
    o[4] = (_Float16)fmaxf(m4, 0.f); o[5] = (_Float16)fmaxf(m5, 0.f);
    o[6] = (_Float16)fmaxf(m6, 0.f); o[7] = (_Float16)fmaxf(m7, 0.f);
    *(half8*)(agg + (size_t)p * 512 + c) = o;
}

// ------- glob[b][c]: inline BN-stat finalize + chunk max/min + affine (exact)
__global__ __launch_bounds__(256) void globred2_kernel(const float* __restrict__ pmx,
                                                       const float* __restrict__ pmn,
                                                       const float* __restrict__ ps,
                                                       const float* __restrict__ pq,
                                                       const float* __restrict__ g,
                                                       const float* __restrict__ bb,
                                                       float* __restrict__ glob)
{
    int c = blockIdx.x * 256 + threadIdx.x;
    int b = blockIdx.y;
    float s = 0.f, q = 0.f;
    for (int ch = 0; ch < STAT_NCH; ++ch) { s += ps[(size_t)ch * 1024 + c]; q += pq[(size_t)ch * 1024 + c]; }
    const float invM = 1.0f / 16384.0f;
    float m  = s * invM;
    float v  = fmaxf(q * invM - m * m, 0.f);
    float sc = g[c] / sqrtf(v + EPSBN);
    float sh = bb[c] - m * sc;
    float mx = -INFINITY, mn = INFINITY;
#pragma unroll
    for (int ch = 0; ch < 16; ++ch) {
        size_t o = (size_t)(b * 16 + ch) * 1024 + c;
        mx = fmaxf(mx, pmx[o]);
        mn = fminf(mn, pmn[o]);
    }
    float vv = (sc >= 0.f) ? mx : mn;
    glob[(size_t)b * 1024 + c] = fmaf(sc, vv, sh);
}

// ------------- final (8x1024)@(1024x512) + BN(8), 64 blocks (col x K split)
__global__ __launch_bounds__(256) void final_kernel(const float* __restrict__ glob,
                                                    const float* __restrict__ w2,
                                                    const float* __restrict__ g,
                                                    const float* __restrict__ bb,
                                                    float* __restrict__ out)
{
    __shared__ float partial[8][8][4];
    __shared__ float vals[8][8];
    int t = threadIdx.x;
    int c8 = blockIdx.x << 3;              // 8 cols per block
    int r = t >> 5, c = (t >> 2) & 7, kq = t & 3;
    const float* gr = glob + (size_t)r * 1024 + (kq << 8);
    const float* wc = w2 + ((size_t)(kq << 8)) * 512 + c8 + c;
    float a = 0.f;
    for (int k = 0; k < 256; ++k)
        a = fmaf(gr[k], wc[(size_t)k * 512], a);
    partial[r][c][kq] = a;
    __syncthreads();
    if (t < 64) {
        int rr = t >> 3, cc = t & 7;
        vals[rr][cc] = partial[rr][cc][0] + partial[rr][cc][1]
                     + partial[rr][cc][2] + partial[rr][cc][3];
    }
    __syncthreads();
    if (t < 8) {
        int cc = t, cg = c8 + t;
        float s = 0.f;
#pragma unroll
        for (int rr = 0; rr < 8; ++rr) s += vals[rr][cc];
        float m = s * 0.125f;
        float v = 0.f;
#pragma unroll
        for (int rr = 0; rr < 8; ++rr) { float d = vals[rr][cc] - m; v = fmaf(d, d, v); }
        v *= 0.125f;
        float sc = g[cg] / sqrtf(v + EPSBN);
#pragma unroll
        for (int rr = 0; rr < 8; ++rr)
            out[(size_t)rr * 512 + cg] = fmaf(vals[rr][cc] - m, sc, bb[cg]);
    }
}

// =============================================================== launch
extern "C" void kernel_launch(void* const* d_in, const int* in_sizes, int n_in,
                              void* d_out, int out_size, void* d_ws, size_t ws_size,
                              hipStream_t stream)
{
    const float* x   = (const float*)d_in[0];
    const float* w1a = (const float*)d_in[1];
    const float* g1a = (const float*)d_in[2];
    const float* b1a = (const float*)d_in[3];
    const float* w1b = (const float*)d_in[4];
    const float* g1b = (const float*)d_in[5];
    const float* b1b = (const float*)d_in[6];
    const float* w1c = (const float*)d_in[7];
    const float* g1c = (const float*)d_in[8];
    const float* b1c = (const float*)d_in[9];
    const float* wg1 = (const float*)d_in[10];
    const float* gg1 = (const float*)d_in[11];
    const float* bg1 = (const float*)d_in[12];
    const float* wg2 = (const float*)d_in[13];
    const float* gg2 = (const float*)d_in[14];
    const float* bg2 = (const float*)d_in[15];
    const float* w2  = (const float*)d_in[16];
    const float* g2  = (const float*)d_in[17];
    const float* b2  = (const float*)d_in[18];

    char* w = (char*)d_ws;
    size_t off = 0;
    auto take = [&](size_t bytes) -> char* {
        char* p = w + off;
        off += (bytes + 255) & ~(size_t)255;
        return p;
    };
    int*       idx     = (int*)      take((size_t)16384 * 16 * 4);
    float*     h0      = (float*)    take((size_t)16384 * 64 * 4);
    float*     h1      = (float*)    take((size_t)16384 * 64 * 4);
    float*     h2      = (float*)    take((size_t)16384 * 64 * 4);
    _Float16*  f512h   = (_Float16*) take((size_t)16384 * 512 * 2);
    _Float16*  f1024h  = (_Float16*) take((size_t)16384 * 1024 * 2);
    _Float16*  aggh64  = (_Float16*) take((size_t)16384 * 64 * 2);
    _Float16*  agg512h = (_Float16*) take((size_t)16384 * 512 * 2);
    _Float16*  w1T     = (_Float16*) take((size_t)512 * 64 * 2);
    _Float16*  w2T     = (_Float16*) take((size_t)1024 * 512 * 2);
    float*     ps      = (float*)    take((size_t)STAT_NCH * 1024 * 4);
    float*     pq      = (float*)    take((size_t)STAT_NCH * 1024 * 4);
    float*     pmx     = (float*)    take((size_t)STAT_NCH * 1024 * 4);
    float*     pmn     = (float*)    take((size_t)STAT_NCH * 1024 * 4);
    float* scA  = (float*)take(64 * 4);   float* shA  = (float*)take(64 * 4);
    float* scB  = (float*)take(64 * 4);   float* shB  = (float*)take(64 * 4);
    float* scC  = (float*)take(64 * 4);   float* shC  = (float*)take(64 * 4);
    float* scG1 = (float*)take(512 * 4);  float* shG1 = (float*)take(512 * 4);
    float* glob = (float*)take((size_t)8 * 1024 * 4);
    (void)ws_size; (void)in_sizes; (void)n_in; (void)out_size;

    const float invM = 1.0f / 16384.0f;

    // merged weight conversion + knn up front
    wtrans2_kernel<<<(64 * 512 + 512 * 1024) / 256, 256, 0, stream>>>(wg1, wg2, w1T, w2T);
    knn_kernel<<<256, 512, 0, stream>>>(x, idx);

    // fused covariance-feature + 19->64 linear (h0 raw) + stats
    cov_lin_kernel<<<256, 256, 0, stream>>>(x, idx, w1a, h0);
    stats_part_kernel<<<dim3(1, STAT_NCH), 256, 0, stream>>>(h0, 64, ps, pq);
    stats_fin_kernel<<<1, 64, 0, stream>>>(ps, pq, 64, invM, g1a, b1a, scA, shA);

    // L1b: bn_relu(h0) @ w1b -> h1 raw, stats on h1
    gemm_bn_kernel<<<dim3(1, 256), 256, 0, stream>>>(h0, w1b, h1, scA, shA, 16384, 64, 64);
    stats_part_kernel<<<dim3(1, STAT_NCH), 256, 0, stream>>>(h1, 64, ps, pq);
    stats_fin_kernel<<<1, 64, 0, stream>>>(ps, pq, 64, invM, g1b, b1b, scB, shB);

    // L1c: bn_relu(h1) @ w1c -> h2 raw, stats on h2
    gemm_bn_kernel<<<dim3(1, 256), 256, 0, stream>>>(h1, w1c, h2, scB, shB, 16384, 64, 64);
    stats_part_kernel<<<dim3(1, STAT_NCH), 256, 0, stream>>>(h2, 64, ps, pq);
    stats_fin_kernel<<<1, 64, 0, stream>>>(ps, pq, 64, invM, g1c, b1c, scC, shC);

    // graph pool 1: gather(bn(h2))-max-relu(f16) then f16 MFMA 64->512 (f16 out)
    gmax1_kernel<<<1024, 256, 0, stream>>>(h2, scC, shC, idx, aggh64);
    hgemm_kernel<<<dim3(4, 128), 256, 0, stream>>>(aggh64, w1T, f512h, 16384, 512, 64);
    stats_part_h_kernel<<<dim3(8, STAT_NCH), 256, 0, stream>>>(f512h, 512, ps, pq);
    stats_fin_kernel<<<8, 64, 0, stream>>>(ps, pq, 512, invM, gg1, bg1, scG1, shG1);

    // graph pool 2: gather(bn)-max-relu(f16) then f16 MFMA 512->1024 (f16 out)
    gmax2_kernel<<<4096, 256, 0, stream>>>(f512h, scG1, shG1, idx, agg512h);
    hgemm_kernel<<<dim3(8, 128), 256, 0, stream>>>(agg512h, w2T, f1024h, 16384, 1024, 512);
    stats_minmax_part_h_kernel<<<dim3(16, STAT_NCH), 256, 0, stream>>>(f1024h, 1024, ps, pq, pmx, pmn);

    // global max via per-chunk raw max/min + inline BN finalize (exact)
    globred2_kernel<<<dim3(4, 8), 256, 0, stream>>>(pmx, pmn, ps, pq, gg2, bg2, glob);

    // final linear + BN over 8 rows (64 blocks, K-split)
    final_kernel<<<64, 256, 0, stream>>>(glob, w2, g2, b2, (float*)d_out);
}